// Round 15
// baseline (443.692 us; speedup 1.0000x reference)
//
#include <hip/hip_runtime.h>

#define NN 100000
#define DD 128
#define RR 8
#define NSEG (RR*NN)          // 800000 segments (etype*N + dst)
#define NB1 782               // ceil(NSEG/1024)
#define ECAP 2048             // per-block LDS edge-index cap

typedef unsigned short u16;
typedef __bf16 bf16x8 __attribute__((ext_vector_type(8)));
typedef float f32x4 __attribute__((ext_vector_type(4)));
typedef u16 ushort4e __attribute__((ext_vector_type(4)));
typedef unsigned int uint4e __attribute__((ext_vector_type(4)));

__device__ __forceinline__ u16 f2bf(float f){
    union { float f; unsigned u; } v; v.f = f;
    unsigned r = v.u + 0x7fffu + ((v.u >> 16) & 1u);
    return (u16)(r >> 16);
}
__device__ __forceinline__ float bf2f(u16 h){
    union { unsigned u; float f; } v; v.u = ((unsigned)h) << 16; return v.f;
}
__device__ __forceinline__ float ftanh(float x){
    float e = __expf(2.0f * x);          // inf-safe: x>>0 -> 1, x<<0 -> -1
    return 1.0f - 2.0f / (e + 1.0f);
}
__device__ __forceinline__ bf16x8 ldv(const u16* p){
    return *reinterpret_cast<const bf16x8*>(p);
}
__device__ __forceinline__ void gload_lds16(const void* g, void* l){
    __builtin_amdgcn_global_load_lds(
        (const __attribute__((address_space(1))) void*)g,
        (__attribute__((address_space(3))) void*)l, 16, 0, 0);
}

// ---- fused prep: cast_x | prep_w | count, one launch (r14, proven) ----
__global__ void k_prep1(const float* __restrict__ x, u16* __restrict__ xb,
                        const float* __restrict__ Wrel, const float* __restrict__ loopw,
                        const float* __restrict__ W1, const float* __restrict__ W2,
                        u16* __restrict__ WT, u16* __restrict__ W1t, u16* __restrict__ W2t,
                        const int* __restrict__ et, const int* __restrict__ dst,
                        int* __restrict__ cnt, int* __restrict__ seg, int E){
    const int bid = blockIdx.x;
    if (bid < 12500){
        int i = (bid * 256 + threadIdx.x) * 4;
        float4 v = *reinterpret_cast<const float4*>(x + i);
        ushort4 o = make_ushort4(f2bf(v.x), f2bf(v.y), f2bf(v.z), f2bf(v.w));
        *reinterpret_cast<ushort4*>(xb + i) = o;
    } else if (bid < 13524){
        int tid = (bid - 12500) * 256 + threadIdx.x;
        if (tid < 131072) {
            int r = tid >> 14, rem = tid & 16383, d = rem >> 7, o = rem & 127;
            WT[(r * 128 + o) * 128 + d] = f2bf(Wrel[tid]);
        } else if (tid < 147456) {
            int i = tid - 131072, d = i >> 7, o = i & 127;
            WT[(8 * 128 + o) * 128 + d] = f2bf(loopw[i]);
        } else if (tid < 212992) {
            int i = tid - 147456, k = i >> 8, n2 = i & 255;
            W1t[n2 * 256 + k] = f2bf(W1[i]);
        } else {
            int i = tid - 212992, k = i >> 7, n2 = i & 127;
            W2t[n2 * 384 + k] = f2bf(W2[i]);
        }
    } else {
        int e = (bid - 13524) * 256 + threadIdx.x;
        if (e < E){
            int s = et[e] * NN + dst[e];
            seg[e] = s;
            atomicAdd(&cnt[s], 1);
        }
    }
}

__global__ void k_scan1(const int* __restrict__ cnt, int* __restrict__ Off, int* __restrict__ bsum){
    __shared__ int lds[256];
    int t = threadIdx.x;
    int i0 = blockIdx.x * 1024 + t * 4;
    int c0 = (i0 + 0 < NSEG) ? cnt[i0 + 0] : 0;
    int c1 = (i0 + 1 < NSEG) ? cnt[i0 + 1] : 0;
    int c2 = (i0 + 2 < NSEG) ? cnt[i0 + 2] : 0;
    int c3 = (i0 + 3 < NSEG) ? cnt[i0 + 3] : 0;
    int s = c0 + c1 + c2 + c3;
    lds[t] = s; __syncthreads();
    for (int off = 1; off < 256; off <<= 1){
        int v = (t >= off) ? lds[t - off] : 0;
        __syncthreads();
        lds[t] += v;
        __syncthreads();
    }
    int excl = lds[t] - s;
    if (i0 + 0 < NSEG) Off[i0 + 0] = excl; excl += c0;
    if (i0 + 1 < NSEG) Off[i0 + 1] = excl; excl += c1;
    if (i0 + 2 < NSEG) Off[i0 + 2] = excl; excl += c2;
    if (i0 + 3 < NSEG) Off[i0 + 3] = excl;
    if (t == 255) bsum[blockIdx.x] = lds[255];
}

// scan3b: per-block redundant prefix over raw block totals (r14, proven)
__global__ void k_scan3b(int* __restrict__ Off, const int* __restrict__ bsum,
                         int* __restrict__ cursor, int E){
    __shared__ int lds[256];
    const int bid = blockIdx.x;
    const int t = threadIdx.x;
    int s = 0;
    for (int j = t; j < bid; j += 256) s += bsum[j];
    lds[t] = s; __syncthreads();
    #pragma unroll
    for (int off = 128; off > 0; off >>= 1){
        if (t < off) lds[t] += lds[t + off];
        __syncthreads();
    }
    const int base = lds[0];
    int i0 = bid * 1024 + t * 4;
    #pragma unroll
    for (int j = 0; j < 4; ++j){
        int i = i0 + j;
        if (i < NSEG){ int v = Off[i] + base; Off[i] = v; cursor[i] = v; }
    }
    if (bid == 0 && t == 0) Off[NSEG] = E;
}

__global__ void k_scatter(const int* __restrict__ seg, const int* __restrict__ src,
                          int* __restrict__ cursor, int* __restrict__ esrc, int E){
    int e = blockIdx.x * 256 + threadIdx.x;
    if (e < E){
        int pos = atomicAdd(&cursor[seg[e]], 1);
        esrc[pos] = src[e];
    }
}

// ---- block-cooperative gather-aggregate (round-6 verbatim, proven 159 us) ----
__global__ __launch_bounds__(256) void k_agg(
    const u16* __restrict__ xb, const int* __restrict__ Off,
    const int* __restrict__ esrc, u16* __restrict__ agg)
{
    __shared__ int offs[33];
    __shared__ int eidx[ECAP];
    const int tid = threadIdx.x;
    const int s0 = blockIdx.x * 32;        // grid = NSEG/32 exact
    if (tid < 33) offs[tid] = Off[s0 + tid];
    __syncthreads();
    const int base = offs[0];
    const int tot = offs[32] - base;
    const bool inlds = (tot <= ECAP);
    if (inlds){
        for (int i = tid; i < tot; i += 256) eidx[i] = esrc[base + i];
    }
    __syncthreads();

    const int hw = tid >> 5;
    const int lid = tid & 31;
    const int c = lid * 4;

    #pragma unroll
    for (int j = 0; j < 4; ++j){
        const int sj = hw * 4 + j;
        const int lo = offs[sj] - base;
        const int hi = offs[sj + 1] - base;
        float a0 = 0.f, a1 = 0.f, a2 = 0.f, a3 = 0.f;
        int e = lo;
        if (inlds){
            for (; e + 4 <= hi; e += 4){
                int i0 = eidx[e], i1 = eidx[e+1], i2 = eidx[e+2], i3 = eidx[e+3];
                ushort4 v0 = *reinterpret_cast<const ushort4*>(xb + (size_t)i0 * DD + c);
                ushort4 v1 = *reinterpret_cast<const ushort4*>(xb + (size_t)i1 * DD + c);
                ushort4 v2 = *reinterpret_cast<const ushort4*>(xb + (size_t)i2 * DD + c);
                ushort4 v3 = *reinterpret_cast<const ushort4*>(xb + (size_t)i3 * DD + c);
                a0 += bf2f(v0.x) + bf2f(v1.x) + bf2f(v2.x) + bf2f(v3.x);
                a1 += bf2f(v0.y) + bf2f(v1.y) + bf2f(v2.y) + bf2f(v3.y);
                a2 += bf2f(v0.z) + bf2f(v1.z) + bf2f(v2.z) + bf2f(v3.z);
                a3 += bf2f(v0.w) + bf2f(v1.w) + bf2f(v2.w) + bf2f(v3.w);
            }
            for (; e < hi; ++e){
                int i = eidx[e];
                ushort4 v = *reinterpret_cast<const ushort4*>(xb + (size_t)i * DD + c);
                a0 += bf2f(v.x); a1 += bf2f(v.y); a2 += bf2f(v.z); a3 += bf2f(v.w);
            }
        } else {
            for (; e < hi; ++e){
                int i = esrc[base + e];
                ushort4 v = *reinterpret_cast<const ushort4*>(xb + (size_t)i * DD + c);
                a0 += bf2f(v.x); a1 += bf2f(v.y); a2 += bf2f(v.z); a3 += bf2f(v.w);
            }
        }
        ushort4e o;
        o.x = f2bf(a0); o.y = f2bf(a1); o.z = f2bf(a2); o.w = f2bf(a3);
        __builtin_nontemporal_store(o,
            reinterpret_cast<ushort4e*>(agg + (size_t)(s0 + sj) * DD + c));
    }
}

// ---- fused MFMA: DEPTH-4 pipeline (4 rotating 16KB buffers) ----
// Tiles 0..7 = agg relations, tile 8 = x (buffer 8&3=0, persists for C/D).
// Prologue: tiles 0-3 in flight (8 loads/wave). Loop: vmcnt(6) keeps tiles
// r+1..r+3 in flight (~3 iterations ~900cyc cover) -> barrier -> MFMA tile r
// -> lgkmcnt(0)+barrier -> issue tile r+4 into vacated buffer.
// LDS 65536 B exactly -> 2 blocks/CU. Post-B: msgs [64][128] swz @buf1,
// mids [64][256] swz @buf2-3 (r13-proven layouts).
__global__ __launch_bounds__(512) void k_fused(
    const u16* __restrict__ xb, const u16* __restrict__ agg,
    const u16* __restrict__ WT, const u16* __restrict__ W1t, const u16* __restrict__ W2t,
    const float* __restrict__ relb, const float* __restrict__ bb1, const float* __restrict__ bb2,
    float* __restrict__ out)
{
    __shared__ __align__(16) u16 smem[32768];
    u16* xt   = smem;                 // buffer 0 (tile 8 = x)
    u16* msgs = smem + 8192;          // post-B, aliases buffer 1
    u16* mids = smem + 16384;         // post-B, aliases buffers 2-3 ([64][256])

    const int tid = threadIdx.x;
    const int w = tid >> 6;
    const int lane = tid & 63;
    const int l15 = lane & 15;
    const int l4 = lane >> 4;
    const int kof = l4 * 8;
    const int swz = (l15 & 7) << 3;   // u16-unit XOR for staged-tile reads
    const int b64 = blockIdx.x * 64;

    // DMA staging (r7/8-proven): LDS byte W = w*1024 + lane*16 (+8192 2nd);
    // row = W>>8 (clamped); in-row src byte = (W&255)^((row&7)<<4).
    const int Wb0 = w * 1024 + (lane << 4);
    auto stage_dma = [&](u16* buf, const u16* grows){
        #pragma unroll
        for (int is = 0; is < 2; ++is){
            int W = Wb0 + is * 8192;
            int row = W >> 8;
            int srcrow = (b64 + row < NN) ? row : 0;
            int inrow = (W & 255) ^ ((row & 7) << 4);
            const char* src = (const char*)(grows + (size_t)srcrow * DD) + inrow;
            gload_lds16(src, (char*)buf + W);
        }
    };

    // ---------- phase B: msg = sum_r agg_r @ W_r + x @ loop_w ----------
    f32x4 acc[4];
    #pragma unroll
    for (int mi = 0; mi < 4; ++mi)
        #pragma unroll
        for (int q = 0; q < 4; ++q) acc[mi][q] = 0.f;

    // prologue: tiles 0..3 (agg relations 0..3) into buffers 0..3
    #pragma unroll
    for (int t = 0; t < 4; ++t)
        stage_dma(smem + t * 8192, agg + ((size_t)t * NN + b64) * DD);

    for (int r = 0; r <= 8; ++r){
        // wait own loads for tile r; keep tiles r+1..r+3 in flight
        __builtin_amdgcn_sched_barrier(0);
        if (r <= 5)      asm volatile("s_waitcnt vmcnt(6)" ::: "memory");
        else if (r == 6) asm volatile("s_waitcnt vmcnt(4)" ::: "memory");
        else if (r == 7) asm volatile("s_waitcnt vmcnt(2)" ::: "memory");
        else             asm volatile("s_waitcnt vmcnt(0)" ::: "memory");
        __builtin_amdgcn_sched_barrier(0);
        __builtin_amdgcn_s_barrier();
        __builtin_amdgcn_sched_barrier(0);

        const u16* A = smem + (r & 3) * 8192;
        const u16* B = WT + r * (DD * DD);
        #pragma unroll
        for (int kc = 0; kc < 4; ++kc){
            int cA = (kc * 32 + kof) ^ swz;
            bf16x8 a0 = ldv(A + (l15) * 128 + cA);
            bf16x8 a1 = ldv(A + (16 + l15) * 128 + cA);
            bf16x8 a2 = ldv(A + (32 + l15) * 128 + cA);
            bf16x8 a3 = ldv(A + (48 + l15) * 128 + cA);
            bf16x8 wv = ldv(B + (w * 16 + l15) * DD + kc * 32 + kof);
            acc[0] = __builtin_amdgcn_mfma_f32_16x16x32_bf16(a0, wv, acc[0], 0, 0, 0);
            acc[1] = __builtin_amdgcn_mfma_f32_16x16x32_bf16(a1, wv, acc[1], 0, 0, 0);
            acc[2] = __builtin_amdgcn_mfma_f32_16x16x32_bf16(a2, wv, acc[2], 0, 0, 0);
            acc[3] = __builtin_amdgcn_mfma_f32_16x16x32_bf16(a3, wv, acc[3], 0, 0, 0);
        }

        // my LDS reads of tile r retired -> barrier -> safe to refill buffer
        asm volatile("s_waitcnt lgkmcnt(0)" ::: "memory");
        __builtin_amdgcn_sched_barrier(0);
        __builtin_amdgcn_s_barrier();
        __builtin_amdgcn_sched_barrier(0);

        if (r <= 3)      stage_dma(smem + (r & 3) * 8192,
                                   agg + ((size_t)(r + 4) * NN + b64) * DD);
        else if (r == 4) stage_dma(smem + 0 * 8192, xb + (size_t)b64 * DD); // tile 8 = x -> buf0
    }

    {   // msgs <- acc + bias (swizzled store; wave owns cols [16w,16w+16))
        int col = w * 16 + l15;
        float bv = relb[col];
        #pragma unroll
        for (int mi = 0; mi < 4; ++mi)
            #pragma unroll
            for (int q = 0; q < 4; ++q){
                int row = mi * 16 + l4 * 4 + q;
                msgs[row * 128 + (col ^ ((row & 7) << 3))] = f2bf(acc[mi][q] + bv);
            }
    }
    __syncthreads();

    // ---------- phase C: mid = tanh([x|msg] @ W1 + b1); cols [32w,32w+32) ----------
    f32x4 acc2[4][2];
    #pragma unroll
    for (int mi = 0; mi < 4; ++mi)
        #pragma unroll
        for (int nj = 0; nj < 2; ++nj)
            #pragma unroll
            for (int q = 0; q < 4; ++q) acc2[mi][nj][q] = 0.f;

    #pragma unroll
    for (int kc = 0; kc < 8; ++kc){
        bf16x8 a[4];
        #pragma unroll
        for (int mi = 0; mi < 4; ++mi){
            int cA = ((kc & 3) * 32 + kof) ^ swz;
            a[mi] = (kc < 4) ? ldv(xt + (mi * 16 + l15) * 128 + cA)
                             : ldv(msgs + (mi * 16 + l15) * 128 + cA);
        }
        #pragma unroll
        for (int nj = 0; nj < 2; ++nj){
            int n2 = w * 32 + nj * 16 + l15;
            bf16x8 wv = ldv(W1t + n2 * 256 + kc * 32 + kof);
            #pragma unroll
            for (int mi = 0; mi < 4; ++mi)
                acc2[mi][nj] = __builtin_amdgcn_mfma_f32_16x16x32_bf16(a[mi], wv, acc2[mi][nj], 0, 0, 0);
        }
    }
    // mids region [32768B,65536B) disjoint from msgs/xt -> no barrier before writes
    #pragma unroll
    for (int nj = 0; nj < 2; ++nj){
        int col = w * 32 + nj * 16 + l15;
        float bv = bb1[col];
        #pragma unroll
        for (int mi = 0; mi < 4; ++mi)
            #pragma unroll
            for (int q = 0; q < 4; ++q){
                int row = mi * 16 + l4 * 4 + q;
                mids[row * 256 + (col ^ ((row & 7) << 3))] = f2bf(ftanh(acc2[mi][nj][q] + bv));
            }
    }
    __syncthreads();

    // ---------- phase D: out = [x|mid] @ W2 + b2; cols [16w,16w+16) ----------
    f32x4 acc3[4];
    #pragma unroll
    for (int mi = 0; mi < 4; ++mi)
        #pragma unroll
        for (int q = 0; q < 4; ++q) acc3[mi][q] = 0.f;

    #pragma unroll
    for (int kc = 0; kc < 12; ++kc){
        bf16x8 a[4];
        #pragma unroll
        for (int mi = 0; mi < 4; ++mi){
            if (kc < 4){
                int cA = (kc * 32 + kof) ^ swz;
                a[mi] = ldv(xt + (mi * 16 + l15) * 128 + cA);
            } else {
                int cA = (((kc - 4) * 32) + kof) ^ swz;
                a[mi] = ldv(mids + (mi * 16 + l15) * 256 + cA);
            }
        }
        bf16x8 wv = ldv(W2t + (w * 16 + l15) * 384 + kc * 32 + kof);
        #pragma unroll
        for (int mi = 0; mi < 4; ++mi)
            acc3[mi] = __builtin_amdgcn_mfma_f32_16x16x32_bf16(a[mi], wv, acc3[mi], 0, 0, 0);
    }

    {
        int col = w * 16 + l15;
        float bv = bb2[col];
        #pragma unroll
        for (int mi = 0; mi < 4; ++mi)
            #pragma unroll
            for (int q = 0; q < 4; ++q){
                int row = b64 + mi * 16 + l4 * 4 + q;
                if (row < NN)
                    __builtin_nontemporal_store(acc3[mi][q] + bv,
                        &out[(size_t)row * DD + col]);
            }
    }
}

extern "C" void kernel_launch(void* const* d_in, const int* in_sizes, int n_in,
                              void* d_out, int out_size, void* d_ws, size_t ws_size,
                              hipStream_t stream){
    const float* x    = (const float*)d_in[0];
    const int*   src  = (const int*)d_in[1];
    const int*   dst  = (const int*)d_in[2];
    const int*   et   = (const int*)d_in[3];
    const float* Wrel = (const float*)d_in[4];
    const float* loopw= (const float*)d_in[5];
    const float* relb = (const float*)d_in[6];
    const float* W1   = (const float*)d_in[7];
    const float* b1   = (const float*)d_in[8];
    const float* W2   = (const float*)d_in[9];
    const float* b2   = (const float*)d_in[10];
    const int E = in_sizes[1];
    float* out = (float*)d_out;

    char* ws = (char*)d_ws;
    u16* xb   = (u16*)(ws);                   // 25,600,000 B
    u16* WT   = (u16*)(ws + 25600000);        //    294,912 B
    u16* W1t  = (u16*)(ws + 25894912);        //    131,072 B
    u16* W2t  = (u16*)(ws + 26025984);        //     98,304 B
    int* cnt  = (int*)(ws + 26124288);        //  3,200,000 B (reused as cursor)
    int* Off  = (int*)(ws + 29324288);        //  3,200,256 B (NSEG+1 ints, padded)
    int* bsum = (int*)(ws + 32524544);        //      4,096 B
    int* esrc = (int*)(ws + 32528640);        //  6,400,000 B
    u16* agg  = (u16*)(ws + 38928640);        // 204,800,000 B
    int* seg  = (int*)(ws + 38928640);        // 6,400,000 B — aliases agg head; dead before k_agg writes
    // total required: 243,728,640 B
    if (ws_size < 243728640UL) return;

    const int gprep = 13524 + (E + 255) / 256;
    hipMemsetAsync(cnt, 0, NSEG * sizeof(int), stream);
    k_prep1<<<gprep, 256, 0, stream>>>(x, xb, Wrel, loopw, W1, W2, WT, W1t, W2t,
                                       et, dst, cnt, seg, E);
    k_scan1<<<NB1, 256, 0, stream>>>(cnt, Off, bsum);
    k_scan3b<<<NB1, 256, 0, stream>>>(Off, bsum, cnt, E);
    k_scatter<<<(E + 255) / 256, 256, 0, stream>>>(seg, src, cnt, esrc, E);
    k_agg<<<NSEG / 32, 256, 0, stream>>>(xb, Off, esrc, agg);
    k_fused<<<(NN + 63) / 64, 512, 0, stream>>>(xb, agg, WT, W1t, W2t, relb, b1, b2, out);
}

// Round 16
// 438.687 us; speedup vs baseline: 1.0114x; 1.0114x over previous
//
#include <hip/hip_runtime.h>

#define NN 100000
#define DD 128
#define RR 8
#define NSEG (RR*NN)          // 800000 segments (etype*N + dst)
#define NB1 782               // ceil(NSEG/1024)
#define ECAP 2048             // per-block LDS edge-index cap

typedef unsigned short u16;
typedef __bf16 bf16x8 __attribute__((ext_vector_type(8)));
typedef float f32x4 __attribute__((ext_vector_type(4)));
typedef u16 ushort4e __attribute__((ext_vector_type(4)));
typedef unsigned int uint4e __attribute__((ext_vector_type(4)));

__device__ __forceinline__ u16 f2bf(float f){
    union { float f; unsigned u; } v; v.f = f;
    unsigned r = v.u + 0x7fffu + ((v.u >> 16) & 1u);
    return (u16)(r >> 16);
}
__device__ __forceinline__ float bf2f(u16 h){
    union { unsigned u; float f; } v; v.u = ((unsigned)h) << 16; return v.f;
}
__device__ __forceinline__ float ftanh(float x){
    float e = __expf(2.0f * x);          // inf-safe: x>>0 -> 1, x<<0 -> -1
    return 1.0f - 2.0f / (e + 1.0f);
}
__device__ __forceinline__ bf16x8 ldv(const u16* p){
    return *reinterpret_cast<const bf16x8*>(p);
}
__device__ __forceinline__ void gload_lds16(const void* g, void* l){
    __builtin_amdgcn_global_load_lds(
        (const __attribute__((address_space(1))) void*)g,
        (__attribute__((address_space(3))) void*)l, 16, 0, 0);
}

// ---- fused prep: cast_x | prep_w | count, one launch (r14, proven) ----
__global__ void k_prep1(const float* __restrict__ x, u16* __restrict__ xb,
                        const float* __restrict__ Wrel, const float* __restrict__ loopw,
                        const float* __restrict__ W1, const float* __restrict__ W2,
                        u16* __restrict__ WT, u16* __restrict__ W1t, u16* __restrict__ W2t,
                        const int* __restrict__ et, const int* __restrict__ dst,
                        int* __restrict__ cnt, int* __restrict__ seg, int E){
    const int bid = blockIdx.x;
    if (bid < 12500){
        // cast x -> bf16 (12500 * 1024 = 12,800,000 = NN*DD exact)
        int i = (bid * 256 + threadIdx.x) * 4;
        float4 v = *reinterpret_cast<const float4*>(x + i);
        ushort4 o = make_ushort4(f2bf(v.x), f2bf(v.y), f2bf(v.z), f2bf(v.w));
        *reinterpret_cast<ushort4*>(xb + i) = o;
    } else if (bid < 13524){
        // weight transposes (1024 * 256 = 262144 exact)
        int tid = (bid - 12500) * 256 + threadIdx.x;
        if (tid < 131072) {
            int r = tid >> 14, rem = tid & 16383, d = rem >> 7, o = rem & 127;
            WT[(r * 128 + o) * 128 + d] = f2bf(Wrel[tid]);
        } else if (tid < 147456) {
            int i = tid - 131072, d = i >> 7, o = i & 127;
            WT[(8 * 128 + o) * 128 + d] = f2bf(loopw[i]);
        } else if (tid < 212992) {
            int i = tid - 147456, k = i >> 8, n2 = i & 255;
            W1t[n2 * 256 + k] = f2bf(W1[i]);
        } else {
            int i = tid - 212992, k = i >> 7, n2 = i & 127;
            W2t[n2 * 384 + k] = f2bf(W2[i]);
        }
    } else {
        // count + cache combined segment id
        int e = (bid - 13524) * 256 + threadIdx.x;
        if (e < E){
            int s = et[e] * NN + dst[e];
            seg[e] = s;
            atomicAdd(&cnt[s], 1);
        }
    }
}

__global__ void k_scan1(const int* __restrict__ cnt, int* __restrict__ Off, int* __restrict__ bsum){
    __shared__ int lds[256];
    int t = threadIdx.x;
    int i0 = blockIdx.x * 1024 + t * 4;
    int c0 = (i0 + 0 < NSEG) ? cnt[i0 + 0] : 0;
    int c1 = (i0 + 1 < NSEG) ? cnt[i0 + 1] : 0;
    int c2 = (i0 + 2 < NSEG) ? cnt[i0 + 2] : 0;
    int c3 = (i0 + 3 < NSEG) ? cnt[i0 + 3] : 0;
    int s = c0 + c1 + c2 + c3;
    lds[t] = s; __syncthreads();
    for (int off = 1; off < 256; off <<= 1){
        int v = (t >= off) ? lds[t - off] : 0;
        __syncthreads();
        lds[t] += v;
        __syncthreads();
    }
    int excl = lds[t] - s;
    if (i0 + 0 < NSEG) Off[i0 + 0] = excl; excl += c0;
    if (i0 + 1 < NSEG) Off[i0 + 1] = excl; excl += c1;
    if (i0 + 2 < NSEG) Off[i0 + 2] = excl; excl += c2;
    if (i0 + 3 < NSEG) Off[i0 + 3] = excl;
    if (t == 255) bsum[blockIdx.x] = lds[255];
}

// scan3b: per-block redundant prefix over raw block totals (replaces scan2+scan3)
__global__ void k_scan3b(int* __restrict__ Off, const int* __restrict__ bsum,
                         int* __restrict__ cursor, int E){
    __shared__ int lds[256];
    const int bid = blockIdx.x;
    const int t = threadIdx.x;
    int s = 0;
    for (int j = t; j < bid; j += 256) s += bsum[j];   // sum of totals of blocks < bid
    lds[t] = s; __syncthreads();
    #pragma unroll
    for (int off = 128; off > 0; off >>= 1){
        if (t < off) lds[t] += lds[t + off];
        __syncthreads();
    }
    const int base = lds[0];
    int i0 = bid * 1024 + t * 4;
    #pragma unroll
    for (int j = 0; j < 4; ++j){
        int i = i0 + j;
        if (i < NSEG){ int v = Off[i] + base; Off[i] = v; cursor[i] = v; }
    }
    if (bid == 0 && t == 0) Off[NSEG] = E;
}

__global__ void k_scatter(const int* __restrict__ seg, const int* __restrict__ src,
                          int* __restrict__ cursor, int* __restrict__ esrc, int E){
    int e = blockIdx.x * 256 + threadIdx.x;
    if (e < E){
        int pos = atomicAdd(&cursor[seg[e]], 1);
        esrc[pos] = src[e];
    }
}

// ---- block-cooperative gather-aggregate (round-6 verbatim, proven 159 us) ----
__global__ __launch_bounds__(256) void k_agg(
    const u16* __restrict__ xb, const int* __restrict__ Off,
    const int* __restrict__ esrc, u16* __restrict__ agg)
{
    __shared__ int offs[33];
    __shared__ int eidx[ECAP];
    const int tid = threadIdx.x;
    const int s0 = blockIdx.x * 32;        // grid = NSEG/32 exact
    if (tid < 33) offs[tid] = Off[s0 + tid];
    __syncthreads();
    const int base = offs[0];
    const int tot = offs[32] - base;
    const bool inlds = (tot <= ECAP);
    if (inlds){
        for (int i = tid; i < tot; i += 256) eidx[i] = esrc[base + i];
    }
    __syncthreads();

    const int hw = tid >> 5;               // half-wave 0..7
    const int lid = tid & 31;
    const int c = lid * 4;

    #pragma unroll
    for (int j = 0; j < 4; ++j){
        const int sj = hw * 4 + j;         // segment-in-block 0..31
        const int lo = offs[sj] - base;
        const int hi = offs[sj + 1] - base;
        float a0 = 0.f, a1 = 0.f, a2 = 0.f, a3 = 0.f;
        int e = lo;
        if (inlds){
            for (; e + 4 <= hi; e += 4){   // 4 independent rows in flight
                int i0 = eidx[e], i1 = eidx[e+1], i2 = eidx[e+2], i3 = eidx[e+3];
                ushort4 v0 = *reinterpret_cast<const ushort4*>(xb + (size_t)i0 * DD + c);
                ushort4 v1 = *reinterpret_cast<const ushort4*>(xb + (size_t)i1 * DD + c);
                ushort4 v2 = *reinterpret_cast<const ushort4*>(xb + (size_t)i2 * DD + c);
                ushort4 v3 = *reinterpret_cast<const ushort4*>(xb + (size_t)i3 * DD + c);
                a0 += bf2f(v0.x) + bf2f(v1.x) + bf2f(v2.x) + bf2f(v3.x);
                a1 += bf2f(v0.y) + bf2f(v1.y) + bf2f(v2.y) + bf2f(v3.y);
                a2 += bf2f(v0.z) + bf2f(v1.z) + bf2f(v2.z) + bf2f(v3.z);
                a3 += bf2f(v0.w) + bf2f(v1.w) + bf2f(v2.w) + bf2f(v3.w);
            }
            for (; e < hi; ++e){
                int i = eidx[e];
                ushort4 v = *reinterpret_cast<const ushort4*>(xb + (size_t)i * DD + c);
                a0 += bf2f(v.x); a1 += bf2f(v.y); a2 += bf2f(v.z); a3 += bf2f(v.w);
            }
        } else {                           // fallback: oversize block range
            for (; e < hi; ++e){
                int i = esrc[base + e];
                ushort4 v = *reinterpret_cast<const ushort4*>(xb + (size_t)i * DD + c);
                a0 += bf2f(v.x); a1 += bf2f(v.y); a2 += bf2f(v.z); a3 += bf2f(v.w);
            }
        }
        ushort4e o;
        o.x = f2bf(a0); o.y = f2bf(a1); o.z = f2bf(a2); o.w = f2bf(a3);
        __builtin_nontemporal_store(o,
            reinterpret_cast<ushort4e*>(agg + (size_t)(s0 + sj) * DD + c));
    }
}

// ---- fused MFMA (round-7 verbatim, proven 437-total config) ----
// DMA staging into unpadded [64][128] tiles, both-sides XOR swizzle.
// LDS (u16): bufA[0,8192) bufB[8192,16384) msgs[16384,25088);
// mids [64][264] aliases smem+8192. 50176 B -> 3 blk/CU.
__global__ __launch_bounds__(512) void k_fused(
    const u16* __restrict__ xb, const u16* __restrict__ agg,
    const u16* __restrict__ WT, const u16* __restrict__ W1t, const u16* __restrict__ W2t,
    const float* __restrict__ relb, const float* __restrict__ bb1, const float* __restrict__ bb2,
    float* __restrict__ out)
{
    __shared__ __align__(16) u16 smem[25088];
    u16 (*bufA)[128] = (u16(*)[128])(smem);
    u16 (*bufB)[128] = (u16(*)[128])(smem + 8192);
    u16 (*msgs)[136] = (u16(*)[136])(smem + 16384);
    u16 (*mids)[264] = (u16(*)[264])(smem + 8192);

    const int tid = threadIdx.x;
    const int w = tid >> 6;          // wave 0..7
    const int lane = tid & 63;
    const int l15 = lane & 15;
    const int l4 = lane >> 4;        // 0..3
    const int kof = l4 * 8;
    const int swz = (l15 & 7) << 3;  // u16-unit XOR for staged-tile reads
    const int b64 = blockIdx.x * 64;

    const int Wb0 = w * 1024 + (lane << 4);
    auto stage_dma = [&](u16* buf, const u16* grows){
        #pragma unroll
        for (int is = 0; is < 2; ++is){
            int W = Wb0 + is * 8192;
            int row = W >> 8;
            int srcrow = (b64 + row < NN) ? row : 0;
            int inrow = (W & 255) ^ ((row & 7) << 4);
            const char* src = (const char*)(grows + (size_t)srcrow * DD) + inrow;
            gload_lds16(src, (char*)buf + W);
        }
    };

    // ---------- phase B: msg = sum_r agg_r @ W_r + x @ loop_w ----------
    f32x4 acc[4];
    #pragma unroll
    for (int mi = 0; mi < 4; ++mi)
        #pragma unroll
        for (int q = 0; q < 4; ++q) acc[mi][q] = 0.f;

    stage_dma(&bufA[0][0], agg + (size_t)b64 * DD);   // relation 0
    __syncthreads();

    for (int r = 0; r <= 8; ++r){
        if (r < 7)       stage_dma((r & 1) ? &bufA[0][0] : &bufB[0][0],
                                   agg + ((size_t)(r + 1) * NN + b64) * DD);
        else if (r == 7) stage_dma(&bufA[0][0], xb + (size_t)b64 * DD);  // x-tile
        const u16 (*A)[128] = (r & 1) ? bufB : bufA;
        const u16* B = WT + r * (DD * DD);
        #pragma unroll
        for (int kc = 0; kc < 4; ++kc){
            int cA = (kc * 32 + kof) ^ swz;
            bf16x8 a0 = ldv(&A[l15][cA]);
            bf16x8 a1 = ldv(&A[16 + l15][cA]);
            bf16x8 a2 = ldv(&A[32 + l15][cA]);
            bf16x8 a3 = ldv(&A[48 + l15][cA]);
            bf16x8 wv = ldv(B + (w * 16 + l15) * DD + kc * 32 + kof);
            acc[0] = __builtin_amdgcn_mfma_f32_16x16x32_bf16(a0, wv, acc[0], 0, 0, 0);
            acc[1] = __builtin_amdgcn_mfma_f32_16x16x32_bf16(a1, wv, acc[1], 0, 0, 0);
            acc[2] = __builtin_amdgcn_mfma_f32_16x16x32_bf16(a2, wv, acc[2], 0, 0, 0);
            acc[3] = __builtin_amdgcn_mfma_f32_16x16x32_bf16(a3, wv, acc[3], 0, 0, 0);
        }
        __syncthreads();
    }

    {   // msgs <- acc + bias   (wave owns cols [16w, 16w+16))
        int col = w * 16 + l15;
        float bv = relb[col];
        #pragma unroll
        for (int mi = 0; mi < 4; ++mi)
            #pragma unroll
            for (int q = 0; q < 4; ++q)
                msgs[mi * 16 + l4 * 4 + q][col] = f2bf(acc[mi][q] + bv);
    }
    __syncthreads();

    // ---------- phase C: mid = tanh([x|msg] @ W1 + b1) ----------
    f32x4 acc2[4][2];
    #pragma unroll
    for (int mi = 0; mi < 4; ++mi)
        #pragma unroll
        for (int nj = 0; nj < 2; ++nj)
            #pragma unroll
            for (int q = 0; q < 4; ++q) acc2[mi][nj][q] = 0.f;

    #pragma unroll
    for (int kc = 0; kc < 8; ++kc){
        bf16x8 a[4];
        #pragma unroll
        for (int mi = 0; mi < 4; ++mi)
            a[mi] = (kc < 4) ? ldv(&bufA[mi * 16 + l15][(kc * 32 + kof) ^ swz])
                             : ldv(&msgs[mi * 16 + l15][(kc - 4) * 32 + kof]);
        #pragma unroll
        for (int nj = 0; nj < 2; ++nj){
            int n2 = w * 32 + nj * 16 + l15;
            bf16x8 wv = ldv(W1t + n2 * 256 + kc * 32 + kof);
            #pragma unroll
            for (int mi = 0; mi < 4; ++mi)
                acc2[mi][nj] = __builtin_amdgcn_mfma_f32_16x16x32_bf16(a[mi], wv, acc2[mi][nj], 0, 0, 0);
        }
    }
    __syncthreads();   // all reads of msgs/bufB region done before mids overwrites it
    #pragma unroll
    for (int nj = 0; nj < 2; ++nj){
        int col = w * 32 + nj * 16 + l15;
        float bv = bb1[col];
        #pragma unroll
        for (int mi = 0; mi < 4; ++mi)
            #pragma unroll
            for (int q = 0; q < 4; ++q)
                mids[mi * 16 + l4 * 4 + q][col] = f2bf(ftanh(acc2[mi][nj][q] + bv));
    }
    __syncthreads();

    // ---------- phase D: out = [x|mid] @ W2 + b2 ----------
    f32x4 acc3[4];
    #pragma unroll
    for (int mi = 0; mi < 4; ++mi)
        #pragma unroll
        for (int q = 0; q < 4; ++q) acc3[mi][q] = 0.f;

    #pragma unroll
    for (int kc = 0; kc < 12; ++kc){
        bf16x8 a[4];
        #pragma unroll
        for (int mi = 0; mi < 4; ++mi)
            a[mi] = (kc < 4) ? ldv(&bufA[mi * 16 + l15][(kc * 32 + kof) ^ swz])
                             : ldv(&mids[mi * 16 + l15][(kc - 4) * 32 + kof]);
        bf16x8 wv = ldv(W2t + (w * 16 + l15) * 384 + kc * 32 + kof);
        #pragma unroll
        for (int mi = 0; mi < 4; ++mi)
            acc3[mi] = __builtin_amdgcn_mfma_f32_16x16x32_bf16(a[mi], wv, acc3[mi], 0, 0, 0);
    }

    {
        int col = w * 16 + l15;
        float bv = bb2[col];
        #pragma unroll
        for (int mi = 0; mi < 4; ++mi)
            #pragma unroll
            for (int q = 0; q < 4; ++q){
                int row = b64 + mi * 16 + l4 * 4 + q;
                if (row < NN)
                    __builtin_nontemporal_store(acc3[mi][q] + bv,
                        &out[(size_t)row * DD + col]);
            }
    }
}

extern "C" void kernel_launch(void* const* d_in, const int* in_sizes, int n_in,
                              void* d_out, int out_size, void* d_ws, size_t ws_size,
                              hipStream_t stream){
    const float* x    = (const float*)d_in[0];
    const int*   src  = (const int*)d_in[1];
    const int*   dst  = (const int*)d_in[2];
    const int*   et   = (const int*)d_in[3];
    const float* Wrel = (const float*)d_in[4];
    const float* loopw= (const float*)d_in[5];
    const float* relb = (const float*)d_in[6];
    const float* W1   = (const float*)d_in[7];
    const float* b1   = (const float*)d_in[8];
    const float* W2   = (const float*)d_in[9];
    const float* b2   = (const float*)d_in[10];
    const int E = in_sizes[1];
    float* out = (float*)d_out;

    char* ws = (char*)d_ws;
    u16* xb   = (u16*)(ws);                   // 25,600,000 B
    u16* WT   = (u16*)(ws + 25600000);        //    294,912 B
    u16* W1t  = (u16*)(ws + 25894912);        //    131,072 B
    u16* W2t  = (u16*)(ws + 26025984);        //     98,304 B
    int* cnt  = (int*)(ws + 26124288);        //  3,200,000 B (reused as cursor)
    int* Off  = (int*)(ws + 29324288);        //  3,200,256 B (NSEG+1 ints, padded)
    int* bsum = (int*)(ws + 32524544);        //      4,096 B
    int* esrc = (int*)(ws + 32528640);        //  6,400,000 B
    u16* agg  = (u16*)(ws + 38928640);        // 204,800,000 B
    int* seg  = (int*)(ws + 38928640);        // 6,400,000 B — aliases agg head; dead before k_agg writes
    // total required: 243,728,640 B
    if (ws_size < 243728640UL) return;

    const int gprep = 13524 + (E + 255) / 256;
    hipMemsetAsync(cnt, 0, NSEG * sizeof(int), stream);
    k_prep1<<<gprep, 256, 0, stream>>>(x, xb, Wrel, loopw, W1, W2, WT, W1t, W2t,
                                       et, dst, cnt, seg, E);
    k_scan1<<<NB1, 256, 0, stream>>>(cnt, Off, bsum);
    k_scan3b<<<NB1, 256, 0, stream>>>(Off, bsum, cnt, E);
    k_scatter<<<(E + 255) / 256, 256, 0, stream>>>(seg, src, cnt, esrc, E);
    k_agg<<<NSEG / 32, 256, 0, stream>>>(xb, Off, esrc, agg);
    k_fused<<<(NN + 63) / 64, 512, 0, stream>>>(xb, agg, WT, W1t, W2t, relb, b1, b2, out);
}